// Round 1
// baseline (360.532 us; speedup 1.0000x reference)
//
#include <hip/hip_runtime.h>
#include <math.h>

#define DIM   2048
#define BATCH 256
#define PN    56          // PATCH_NUM - MASK_NUM
constexpr float KD_T = 4.0f;

// ---------------- wave/block reduction helpers (wave = 64) ----------------
__device__ __forceinline__ float wave_max(float v) {
#pragma unroll
    for (int o = 32; o > 0; o >>= 1) v = fmaxf(v, __shfl_xor(v, o, 64));
    return v;
}
__device__ __forceinline__ float wave_sum(float v) {
#pragma unroll
    for (int o = 32; o > 0; o >>= 1) v += __shfl_xor(v, o, 64);
    return v;
}

// ---------------- kernel 1: ebp_bar = mean over P ----------------
// one thread per float4 of [B, D]; p-slices are 2MB apart, coalesced across lanes
__global__ void __launch_bounds__(256) bar_kernel(const float* __restrict__ ebp,
                                                  float* __restrict__ bar) {
    int idx = blockIdx.x * 256 + threadIdx.x;      // 0 .. B*D/4-1
    const float4* ep = (const float4*)ebp;
    float x = 0.f, y = 0.f, z = 0.f, w = 0.f;
#pragma unroll 8
    for (int p = 0; p < PN; ++p) {
        float4 v = ep[(size_t)p * (BATCH * DIM / 4) + idx];
        x += v.x; y += v.y; z += v.z; w += v.w;
    }
    const float inv = 1.0f / PN;
    float4 o; o.x = x * inv; o.y = y * inv; o.z = z * inv; o.w = w * inv;
    ((float4*)bar)[idx] = o;
}

// ---------------- kernel 2: soft_dil ----------------
// one block per batch row; symmetric KL of ebg[b,:] vs bar[b,:]
__global__ void __launch_bounds__(256) dil_kernel(const float* __restrict__ ebg,
                                                  const float* __restrict__ bar,
                                                  double* __restrict__ acc) {
    __shared__ float sred[8];
    const int b = blockIdx.x, t = threadIdx.x;
    const float4* g4 = (const float4*)(ebg + (size_t)b * DIM);
    const float4* m4 = (const float4*)(bar + (size_t)b * DIM);
    const float invT = 1.0f / KD_T;

    float s[8], tt[8];
    float smax = -INFINITY, tmax = -INFINITY;
#pragma unroll
    for (int i = 0; i < 2; ++i) {
        float4 g = g4[2 * t + i], m = m4[2 * t + i];
        float gs[4] = {g.x, g.y, g.z, g.w};
        float ms[4] = {m.x, m.y, m.z, m.w};
#pragma unroll
        for (int j = 0; j < 4; ++j) {
            float sv = gs[j] * invT, tv = ms[j] * invT;
            s[i * 4 + j] = sv; tt[i * 4 + j] = tv;
            smax = fmaxf(smax, sv); tmax = fmaxf(tmax, tv);
        }
    }
    smax = wave_max(smax); tmax = wave_max(tmax);
    const int lane = t & 63, wv = t >> 6;
    if (lane == 0) { sred[wv] = smax; sred[4 + wv] = tmax; }
    __syncthreads();
    smax = fmaxf(fmaxf(sred[0], sred[1]), fmaxf(sred[2], sred[3]));
    tmax = fmaxf(fmaxf(sred[4], sred[5]), fmaxf(sred[6], sred[7]));
    __syncthreads();

    float es[8], et[8], ssum = 0.f, tsum = 0.f;
#pragma unroll
    for (int i = 0; i < 8; ++i) {
        es[i] = __expf(s[i] - smax);  ssum += es[i];
        et[i] = __expf(tt[i] - tmax); tsum += et[i];
    }
    ssum = wave_sum(ssum); tsum = wave_sum(tsum);
    if (lane == 0) { sred[wv] = ssum; sred[4 + wv] = tsum; }
    __syncthreads();
    ssum = sred[0] + sred[1] + sred[2] + sred[3];
    tsum = sred[4] + sred[5] + sred[6] + sred[7];
    __syncthreads();

    const float invs = 1.0f / ssum, invt = 1.0f / tsum;
    float r = 0.f;
#pragma unroll
    for (int i = 0; i < 8; ++i)
        r += (et[i] * invt - es[i] * invs) * (tt[i] - s[i]);
    r = wave_sum(r);
    if (lane == 0) sred[wv] = r;
    __syncthreads();
    if (t == 0) {
        float tot = (sred[0] + sred[1] + sred[2] + sred[3]) * (KD_T * KD_T / DIM);
        atomicAdd(acc, (double)tot);
    }
}

// ---------------- kernel 3: soft_dcl ----------------
// one block per (b,p) pair; row = p*BATCH + b so consecutive blocks stream
// consecutive ebp rows; ebg/bar (2MB each) stay L2/LLC-resident
__global__ void __launch_bounds__(256) dcl_kernel(const float* __restrict__ ebg,
                                                  const float* __restrict__ ebp,
                                                  const float* __restrict__ bar,
                                                  double* __restrict__ acc) {
    __shared__ float sred[8];
    const int row = blockIdx.x;
    const int b = row & (BATCH - 1);
    const int p = row >> 8;
    const int t = threadIdx.x;
    const float4* g4 = (const float4*)(ebg + (size_t)b * DIM);
    const float4* m4 = (const float4*)(bar + (size_t)b * DIM);
    const float4* e4 = (const float4*)(ebp + ((size_t)p * BATCH + b) * DIM);
    const float invT = 1.0f / KD_T;

    float a[8], c[8];               // a = dg/T, c = db/T
    float amax = -INFINITY, cmax = -INFINITY;
#pragma unroll
    for (int i = 0; i < 2; ++i) {
        float4 g = g4[2 * t + i], m = m4[2 * t + i], e = e4[2 * t + i];
        float gs[4] = {g.x, g.y, g.z, g.w};
        float ms[4] = {m.x, m.y, m.z, m.w};
        float es_[4] = {e.x, e.y, e.z, e.w};
#pragma unroll
        for (int j = 0; j < 4; ++j) {
            float dg = gs[j] - es_[j];
            float db = ms[j] - es_[j];
            float av = dg * dg * invT;
            float cv = db * db * invT;
            a[i * 4 + j] = av; c[i * 4 + j] = cv;
            amax = fmaxf(amax, av); cmax = fmaxf(cmax, cv);
        }
    }
    amax = wave_max(amax); cmax = wave_max(cmax);
    const int lane = t & 63, wv = t >> 6;
    if (lane == 0) { sred[wv] = amax; sred[4 + wv] = cmax; }
    __syncthreads();
    amax = fmaxf(fmaxf(sred[0], sred[1]), fmaxf(sred[2], sred[3]));
    cmax = fmaxf(fmaxf(sred[4], sred[5]), fmaxf(sred[6], sred[7]));
    __syncthreads();

    float ea[8], ec[8], asum = 0.f, csum = 0.f;
#pragma unroll
    for (int i = 0; i < 8; ++i) {
        ea[i] = __expf(a[i] - amax); asum += ea[i];
        ec[i] = __expf(c[i] - cmax); csum += ec[i];
    }
    asum = wave_sum(asum); csum = wave_sum(csum);
    if (lane == 0) { sred[wv] = asum; sred[4 + wv] = csum; }
    __syncthreads();
    asum = sred[0] + sred[1] + sred[2] + sred[3];
    csum = sred[4] + sred[5] + sred[6] + sred[7];
    __syncthreads();

    const float inva = 1.0f / asum, invc = 1.0f / csum;
    float r = 0.f;
#pragma unroll
    for (int i = 0; i < 8; ++i)
        r += (ec[i] * invc - ea[i] * inva) * (c[i] - a[i]);
    r = wave_sum(r);
    if (lane == 0) sred[wv] = r;
    __syncthreads();
    if (t == 0) {
        float tot = (sred[0] + sred[1] + sred[2] + sred[3]) *
                    (KD_T * KD_T / (float)DIM / (float)PN);
        atomicAdd(acc, (double)tot);
    }
}

// ---------------- finalize: double accumulators -> float outputs ----------------
__global__ void finalize_kernel(const double* __restrict__ acc, float* __restrict__ out) {
    if (threadIdx.x == 0) {
        out[0] = (float)acc[0];
        out[1] = (float)acc[1];
    }
}

extern "C" void kernel_launch(void* const* d_in, const int* in_sizes, int n_in,
                              void* d_out, int out_size, void* d_ws, size_t ws_size,
                              hipStream_t stream) {
    const float* ebg = (const float*)d_in[0];
    const float* ebp = (const float*)d_in[1];
    // labels (d_in[2]) unused by the forward computation

    double* acc = (double*)d_ws;                    // acc[0]=dil, acc[1]=dcl
    float*  bar = (float*)((char*)d_ws + 16);       // [BATCH, DIM] fp32, 2 MB

    hipMemsetAsync(d_ws, 0, 16, stream);            // zero the two accumulators
    bar_kernel<<<BATCH * DIM / 4 / 256, 256, 0, stream>>>(ebp, bar);
    dil_kernel<<<BATCH, 256, 0, stream>>>(ebg, bar, acc);
    dcl_kernel<<<BATCH * PN, 256, 0, stream>>>(ebg, ebp, bar, acc + 1);
    finalize_kernel<<<1, 64, 0, stream>>>(acc, (float*)d_out);
}

// Round 2
// 202.856 us; speedup vs baseline: 1.7773x; 1.7773x over previous
//
#include <hip/hip_runtime.h>
#include <math.h>

#define DIM   2048
#define BATCH 256
#define PN    56          // PATCH_NUM - MASK_NUM
constexpr float KD_T = 4.0f;

#define DCL_BLOCKS 896    // x4 waves x4 rows = 14336 rows
#define DIL_BLOCKS 64     // x4 waves x1 row  = 256 rows

// ---------------- reduction helpers (wave = 64) ----------------
__device__ __forceinline__ float wave_sum(float v) {
#pragma unroll
    for (int o = 32; o > 0; o >>= 1) v += __shfl_xor(v, o, 64);
    return v;
}
__device__ __forceinline__ double wave_sum_d(double v) {
#pragma unroll
    for (int o = 32; o > 0; o >>= 1) v += __shfl_xor(v, o, 64);
    return v;
}

// ---------------- kernel 1: ebp_bar = mean over P ----------------
__global__ void __launch_bounds__(256) bar_kernel(const float* __restrict__ ebp,
                                                  float* __restrict__ bar) {
    int idx = blockIdx.x * 256 + threadIdx.x;      // 0 .. B*D/4-1
    const float4* ep = (const float4*)ebp;
    float x = 0.f, y = 0.f, z = 0.f, w = 0.f;
#pragma unroll 8
    for (int p = 0; p < PN; ++p) {
        float4 v = ep[(size_t)p * (BATCH * DIM / 4) + idx];
        x += v.x; y += v.y; z += v.z; w += v.w;
    }
    const float inv = 1.0f / PN;
    float4 o; o.x = x * inv; o.y = y * inv; o.z = z * inv; o.w = w * inv;
    ((float4*)bar)[idx] = o;
}

// ---------------- kernel 2: soft_dil (wave-per-row, one pass) ----------------
// sym-KL(x,y) = sum (p_t - p_s)(t - s);  s=x/T, t=y/T  (logsumexp terms cancel)
__global__ void __launch_bounds__(256) dil_kernel(const float* __restrict__ ebg,
                                                  const float* __restrict__ bar,
                                                  double* __restrict__ partial) {
    __shared__ double sd[4];
    const int lane = threadIdx.x & 63;
    const int wv   = threadIdx.x >> 6;
    const int row  = blockIdx.x * 4 + wv;          // 0..255, one row per wave
    const float4* g4 = (const float4*)(ebg + (size_t)row * DIM);
    const float4* m4 = (const float4*)(bar + (size_t)row * DIM);
    const float invT = 1.0f / KD_T;

    float ssum = 0.f, tsum = 0.f, t1 = 0.f, t2 = 0.f;
#pragma unroll
    for (int j = 0; j < 8; ++j) {
        float4 g = g4[j * 64 + lane];
        float4 m = m4[j * 64 + lane];
        float gs[4] = {g.x, g.y, g.z, g.w};
        float ms[4] = {m.x, m.y, m.z, m.w};
#pragma unroll
        for (int k = 0; k < 4; ++k) {
            float s = gs[k] * invT, t = ms[k] * invT;
            float es = __expf(s), et = __expf(t);
            float d = t - s;
            ssum += es; tsum += et;
            t1 = fmaf(es, d, t1);
            t2 = fmaf(et, d, t2);
        }
    }
    ssum = wave_sum(ssum); tsum = wave_sum(tsum);
    t1 = wave_sum(t1);     t2 = wave_sum(t2);
    double r = (double)(t2 / tsum - t1 / ssum);
    if (lane == 0) sd[wv] = r;
    __syncthreads();
    if (threadIdx.x == 0)
        partial[blockIdx.x] = (sd[0] + sd[1] + sd[2] + sd[3]) *
                              ((double)KD_T * KD_T / (double)DIM);
}

// ---------------- kernel 3: soft_dcl (wave-per-row, one pass, grid-stride) --
__global__ void __launch_bounds__(256) dcl_kernel(const float* __restrict__ ebg,
                                                  const float* __restrict__ ebp,
                                                  const float* __restrict__ bar,
                                                  double* __restrict__ partial) {
    __shared__ double sd[4];
    const int lane  = threadIdx.x & 63;
    const int wv    = threadIdx.x >> 6;
    const int gwave = blockIdx.x * 4 + wv;
    const int nwav  = DCL_BLOCKS * 4;
    const float invT = 1.0f / KD_T;

    double dacc = 0.0;
    for (int row = gwave; row < BATCH * PN; row += nwav) {
        const int b = row & (BATCH - 1);
        const float4* g4 = (const float4*)(ebg + (size_t)b * DIM);
        const float4* m4 = (const float4*)(bar + (size_t)b * DIM);
        const float4* e4 = (const float4*)(ebp + (size_t)row * DIM);

        float asum = 0.f, csum = 0.f, t1 = 0.f, t2 = 0.f;
#pragma unroll
        for (int j = 0; j < 8; ++j) {
            float4 g = g4[j * 64 + lane];
            float4 m = m4[j * 64 + lane];
            float4 e = e4[j * 64 + lane];
            float gs[4] = {g.x, g.y, g.z, g.w};
            float ms[4] = {m.x, m.y, m.z, m.w};
            float es[4] = {e.x, e.y, e.z, e.w};
#pragma unroll
            for (int k = 0; k < 4; ++k) {
                float dg = gs[k] - es[k];
                float db = ms[k] - es[k];
                float a = dg * dg * invT;
                float c = db * db * invT;
                float ea = __expf(a), ec = __expf(c);
                float d = c - a;
                asum += ea; csum += ec;
                t1 = fmaf(ea, d, t1);
                t2 = fmaf(ec, d, t2);
            }
        }
        asum = wave_sum(asum); csum = wave_sum(csum);
        t1 = wave_sum(t1);     t2 = wave_sum(t2);
        dacc += (double)(t2 / csum - t1 / asum);
    }
    if (lane == 0) sd[wv] = dacc;
    __syncthreads();
    if (threadIdx.x == 0)
        partial[blockIdx.x] = (sd[0] + sd[1] + sd[2] + sd[3]) *
                              ((double)KD_T * KD_T / (double)DIM / (double)PN);
}

// ---------------- finalize: reduce partials -> 2 float outputs ----------------
__global__ void __launch_bounds__(256) finalize_kernel(const double* __restrict__ pdcl,
                                                       const double* __restrict__ pdil,
                                                       float* __restrict__ out) {
    __shared__ double sdc[4], sdl[4];
    const int t = threadIdx.x, lane = t & 63, wv = t >> 6;
    double vd = 0.0, vl = 0.0;
    for (int i = t; i < DCL_BLOCKS; i += 256) vd += pdcl[i];
    for (int i = t; i < DIL_BLOCKS; i += 256) vl += pdil[i];
    vd = wave_sum_d(vd); vl = wave_sum_d(vl);
    if (lane == 0) { sdc[wv] = vd; sdl[wv] = vl; }
    __syncthreads();
    if (t == 0) {
        out[0] = (float)(sdl[0] + sdl[1] + sdl[2] + sdl[3]);   // soft_dil
        out[1] = (float)(sdc[0] + sdc[1] + sdc[2] + sdc[3]);   // soft_dcl
    }
}

extern "C" void kernel_launch(void* const* d_in, const int* in_sizes, int n_in,
                              void* d_out, int out_size, void* d_ws, size_t ws_size,
                              hipStream_t stream) {
    const float* ebg = (const float*)d_in[0];
    const float* ebp = (const float*)d_in[1];
    // labels (d_in[2]) unused by the forward computation

    double* pdcl = (double*)d_ws;                         // [896]
    double* pdil = pdcl + DCL_BLOCKS;                     // [64]
    float*  bar  = (float*)((char*)d_ws + 8192);          // [BATCH, DIM] fp32, 2 MB

    bar_kernel<<<BATCH * DIM / 4 / 256, 256, 0, stream>>>(ebp, bar);
    dil_kernel<<<DIL_BLOCKS, 256, 0, stream>>>(ebg, bar, pdil);
    dcl_kernel<<<DCL_BLOCKS, 256, 0, stream>>>(ebg, ebp, bar, pdcl);
    finalize_kernel<<<1, 256, 0, stream>>>(pdcl, pdil, (float*)d_out);
}